// Round 2
// baseline (209.279 us; speedup 1.0000x reference)
//
#include <hip/hip_runtime.h>

// LRN_19705309954750 — cross-channel banded LRN on [B=64, C=128, H=56, W=56] fp32.
// y[c] = sum_{d=-8..8} x[(c+d)%128]^2 ; out = x * (y*ALPHA/17 + 1)^(-0.75)
// Memory-bound: sliding-window channel sum, float4 vectorized over W.
// pow via HW transcendentals: (1+t)^-0.75 = exp2(-0.75*log2(1+t))
// (v_log_f32 / v_exp_f32 — __exp2f/__log2f are CUDA-only and broke the HIP build).

#define B_DIM 64
#define C_DIM 128
#define HW_DIM (56 * 56)      // 3136
#define HW4 (HW_DIM / 4)      // 784 float4 columns per (b, c) plane
#define NSEG 4                // channel segments per column
#define SEGC (C_DIM / NSEG)   // 32 channels per thread

__device__ __forceinline__ float pow_m075(float t) {
    // t in [1, ~1.01]; HW log2 + exp2, ~1 ulp approx each — way inside 0.108 absmax
    return __builtin_amdgcn_exp2f(-0.75f * __builtin_amdgcn_logf(t));
}

__global__ __launch_bounds__(256) void lrn_kernel(const float4* __restrict__ x,
                                                  float4* __restrict__ out) {
    const float kAlphaOverR = 0.001f / 17.0f;

    const int col = blockIdx.x * blockDim.x + threadIdx.x;   // [0, B*HW4)
    const int b   = col / HW4;
    const int hw4 = col - b * HW4;
    const int c0  = blockIdx.y * SEGC;                        // segment start channel

    const float4* base = x + ((size_t)b * C_DIM) * HW4 + hw4; // channel stride = HW4
    float4* obase      = out + ((size_t)b * C_DIM) * HW4 + hw4;

    // Init window sum for c = c0: channels (c0-8 .. c0+8) mod 128
    float4 s = make_float4(0.f, 0.f, 0.f, 0.f);
#pragma unroll
    for (int d = -8; d <= 8; ++d) {
        const int ch = (c0 + d + C_DIM) & (C_DIM - 1);
        const float4 v = base[(size_t)ch * HW4];
        s.x += v.x * v.x;
        s.y += v.y * v.y;
        s.z += v.z * v.z;
        s.w += v.w * v.w;
    }

#pragma unroll 8
    for (int i = 0; i < SEGC; ++i) {
        const int c = c0 + i;                     // in [c0, c0+31], no mod needed
        const float4 xc = base[(size_t)c * HW4];  // numerator (L1 hit — loaded 8 iters ago)

        float4 r;
        r.x = xc.x * pow_m075(fmaf(s.x, kAlphaOverR, 1.0f));
        r.y = xc.y * pow_m075(fmaf(s.y, kAlphaOverR, 1.0f));
        r.z = xc.z * pow_m075(fmaf(s.z, kAlphaOverR, 1.0f));
        r.w = xc.w * pow_m075(fmaf(s.w, kAlphaOverR, 1.0f));
        obase[(size_t)c * HW4] = r;

        // Slide window: c -> c+1 adds channel (c+9), drops (c-8), both mod 128
        const int ci = (c + 9) & (C_DIM - 1);
        const int co = (c - 8 + C_DIM) & (C_DIM - 1);
        const float4 vin  = base[(size_t)ci * HW4];
        const float4 vout = base[(size_t)co * HW4];
        s.x += vin.x * vin.x - vout.x * vout.x;
        s.y += vin.y * vin.y - vout.y * vout.y;
        s.z += vin.z * vin.z - vout.z * vout.z;
        s.w += vin.w * vin.w - vout.w * vout.w;
    }
}

extern "C" void kernel_launch(void* const* d_in, const int* in_sizes, int n_in,
                              void* d_out, int out_size, void* d_ws, size_t ws_size,
                              hipStream_t stream) {
    const float4* x = (const float4*)d_in[0];   // [64,128,56,56] fp32
    // d_in[1] (inhiMat) is a constant circulant band — computed analytically, unused.
    float4* out = (float4*)d_out;

    // B*HW4 = 64*784 = 50176 threads per segment; 50176/256 = 196 blocks; 4 segments.
    dim3 grid(196, NSEG);
    lrn_kernel<<<grid, 256, 0, stream>>>(x, out);
}

// Round 3
// 193.489 us; speedup vs baseline: 1.0816x; 1.0816x over previous
//
#include <hip/hip_runtime.h>

// LRN_19705309954750 — cross-channel banded LRN on [B=64, C=128, H=56, W=56] fp32.
// y[c] = sum_{d=-8..8} x[(c+d)%128]^2 ; out = x * (y*ALPHA/17 + 1)^(-0.75)
//
// R2 post-mortem: FETCH 170 MB vs 103 MB ideal = 1.65x — exactly the 4-segment
// halo (49 planes read per 32 produced). This version: NSEG=1 (full sliding
// window per thread, zero halo) + float2 columns + single-wave blocks so the
// grid stays fine-grained (1568 blocks, ~6 waves/CU, good CU load balance).

#define B_DIM 64
#define C_DIM 128
#define HW_DIM (56 * 56)      // 3136
#define HW2 (HW_DIM / 2)      // 1568 float2 columns per (b, c) plane
#define NCOL (B_DIM * HW2)    // 100352 total float2 columns

__device__ __forceinline__ float pow_m075(float t) {
    // t in [1, ~1.01]; HW log2 + exp2 (~1 ulp each) — far inside 0.108 absmax
    return __builtin_amdgcn_exp2f(-0.75f * __builtin_amdgcn_logf(t));
}

__global__ __launch_bounds__(64) void lrn_kernel(const float2* __restrict__ x,
                                                 float2* __restrict__ out) {
    const float kAlphaOverR = 0.001f / 17.0f;

    const int col = blockIdx.x * 64 + threadIdx.x;   // [0, NCOL)
    const int b   = col / HW2;
    const int hw2 = col - b * HW2;

    const float2* base = x + ((size_t)b * C_DIM) * HW2 + hw2; // channel stride = HW2
    float2* obase      = out + ((size_t)b * C_DIM) * HW2 + hw2;

    // Init window sum for c = 0: channels (-8 .. 8) mod 128
    float sx = 0.f, sy = 0.f;
#pragma unroll
    for (int d = -8; d <= 8; ++d) {
        const int ch = (d + C_DIM) & (C_DIM - 1);
        const float2 v = base[(size_t)ch * HW2];
        sx += v.x * v.x;
        sy += v.y * v.y;
    }

    // Walk all 128 channels — every plane fetched exactly once from HBM;
    // repeated touches (numerator @c, window-out @c-8) are L1/L2 hits.
#pragma unroll 8
    for (int c = 0; c < C_DIM; ++c) {
        const float2 xc = base[(size_t)c * HW2];

        float2 r;
        r.x = xc.x * pow_m075(fmaf(sx, kAlphaOverR, 1.0f));
        r.y = xc.y * pow_m075(fmaf(sy, kAlphaOverR, 1.0f));
        obase[(size_t)c * HW2] = r;

        const int ci = (c + 9) & (C_DIM - 1);
        const int co = (c - 8 + C_DIM) & (C_DIM - 1);
        const float2 vin  = base[(size_t)ci * HW2];
        const float2 vout = base[(size_t)co * HW2];
        sx += vin.x * vin.x - vout.x * vout.x;
        sy += vin.y * vin.y - vout.y * vout.y;
    }
}

extern "C" void kernel_launch(void* const* d_in, const int* in_sizes, int n_in,
                              void* d_out, int out_size, void* d_ws, size_t ws_size,
                              hipStream_t stream) {
    const float2* x = (const float2*)d_in[0];   // [64,128,56,56] fp32
    // d_in[1] (inhiMat) is a constant circulant band — computed analytically, unused.
    float2* out = (float2*)d_out;

    // NCOL / 64 = 1568 single-wave blocks (~6 waves/CU, fine-grained balance)
    lrn_kernel<<<NCOL / 64, 64, 0, stream>>>(x, out);
}